// Round 6
// baseline (917.827 us; speedup 1.0000x reference)
//
#include <hip/hip_runtime.h>
#include <stdint.h>
#include <math.h>

// Problem constants
constexpr int Bb = 8, Tt = 512, Hh = 2048, Vv = 32000;
constexpr int M = Bb * Tt;     // 4096 tokens
constexpr int K = Hh;          // 2048
constexpr int N = Vv;          // 32000 vocab
constexpr int BM = 256, BN = 256, BK = 64;
constexpr int MBLK = M / BM;   // 16
constexpr int NBLK = N / BN;   // 125 column blocks
constexpr int KTILES = K / BK; // 32 (even)
constexpr int IGNORE = -100;

typedef __attribute__((ext_vector_type(8))) short bf16x8;
typedef __attribute__((ext_vector_type(4))) float f32x4;
typedef __attribute__((ext_vector_type(4))) unsigned short u16x4;

__device__ inline void gld16(const void* g, void* l) {
  __builtin_amdgcn_global_load_lds(
      (const __attribute__((address_space(1))) uint32_t*)g,
      (__attribute__((address_space(3))) uint32_t*)l, 16, 0, 0);
}

// raw s_barrier with compiler memory fences on both sides (NOT __syncthreads:
// that drains vmcnt(0) and kills the counted-vmcnt pipeline).
__device__ __forceinline__ void barrier_f() {
  asm volatile("" ::: "memory");
  __builtin_amdgcn_s_barrier();
  asm volatile("" ::: "memory");
}

__device__ inline unsigned short f2bf(float f) {
  union { float f; unsigned u; } x; x.f = f;
  unsigned r = x.u + 0x7fffu + ((x.u >> 16) & 1u);  // RNE
  return (unsigned short)(r >> 16);
}

// ---------------- fused fp32 -> bf16 cast for X and W (one launch) ----------
// Unit-stride 16B loads / 8B stores. Nontemporal loads keep the dead f32
// stream from evicting the freshly written bf16 W (which the GEMM re-reads
// from L3) -- measured: GEMM FETCH 738->618 MB.
constexpr int NX4 = M * K / 4;               // 2,097,152
constexpr int NW4 = N * K / 4;               // 16,384,000
__global__ __launch_bounds__(256)
void cast_fused(const float* __restrict__ Xf, unsigned short* __restrict__ Xb,
                const float* __restrict__ Wf, unsigned short* __restrict__ Wb) {
  int64_t i = (int64_t)blockIdx.x * blockDim.x + threadIdx.x;
  const int64_t stride = (int64_t)gridDim.x * blockDim.x;
  for (; i < (int64_t)NX4 + NW4; i += stride) {
    const f32x4* s4;
    u16x4* d4;
    int64_t j;
    if (i < NX4) { s4 = (const f32x4*)Xf; d4 = (u16x4*)Xb; j = i; }
    else         { s4 = (const f32x4*)Wf; d4 = (u16x4*)Wb; j = i - NX4; }
    f32x4 v = __builtin_nontemporal_load(&s4[j]);
    u16x4 o;
    o[0] = f2bf(v[0]); o[1] = f2bf(v[1]); o[2] = f2bf(v[2]); o[3] = f2bf(v[3]);
    d4[j] = o;
  }
}

// ---------------- 256x256 8-phase GEMM + fused softmax-stats epilogue --------
// R1 structure (verified absmax 0) with R6 change: LOOSENED COUNTED WAITS.
// R1/R5 used vmcnt(4) at p4/p8, which forces completion of loads issued only
// 3 phases (~900-1100 cyc) earlier -- exactly HBM-miss latency, so every L2
// miss stalled the wait (MfmaUtil stuck at 44%). Dependency analysis: reads
// only need {p1,p2 by p7; p3,p4 by next-p1; prev-p5,p6 by p3; prev-p7,p8 by
// p5}. New schedule: vmcnt(8) at EVERY even phase gives each load 4-6 phases
// (1300-2000 cyc) issue->forced-complete, preserving the exact dependency
// chain (max 12 outstanding). Tail iter: vmcnt 8/4/0 at p2/p4/p6 (once per
// block). Loads, barriers, LDS layout, swizzle all unchanged.

template <int BUF, int KS, int MH, int VM, class STG>
__device__ __forceinline__ void phase(const unsigned short* __restrict__ AsB,
                                      const unsigned short* __restrict__ BsB,
                                      const int* offA, const int* offB,
                                      bf16x8 (&bfrag)[4], f32x4 (&acc)[8][4],
                                      STG&& stg) {
  const unsigned short* Ab = AsB + (BUF * 2 + KS) * 8192;
  if (MH == 0) {  // B fragments loaded once per K-subtile, reused by MH==1
    const unsigned short* Bp = BsB + (BUF * 2 + KS) * 8192;
#pragma unroll
    for (int nf = 0; nf < 4; ++nf) bfrag[nf] = *(const bf16x8*)(Bp + offB[nf]);
  }
  bf16x8 af[4];
#pragma unroll
  for (int mi = 0; mi < 4; ++mi) af[mi] = *(const bf16x8*)(Ab + offA[MH * 4 + mi]);
  stg();
  if (VM == 8) asm volatile("s_waitcnt vmcnt(8)" ::: "memory");
  if (VM == 4) asm volatile("s_waitcnt vmcnt(4)" ::: "memory");
  if (VM == 0) asm volatile("s_waitcnt vmcnt(0)" ::: "memory");
  barrier_f();
  asm volatile("s_waitcnt lgkmcnt(0)" ::: "memory");
  __builtin_amdgcn_s_setprio(1);
#pragma unroll
  for (int mi = 0; mi < 4; ++mi)
#pragma unroll
    for (int nf = 0; nf < 4; ++nf)
      acc[MH * 4 + mi][nf] = __builtin_amdgcn_mfma_f32_16x16x32_bf16(
          af[mi], bfrag[nf], acc[MH * 4 + mi][nf], 0, 0, 0);
  __builtin_amdgcn_s_setprio(0);
  barrier_f();
}

__global__ __launch_bounds__(512, 2)
void gemm_stats(const unsigned short* __restrict__ X,
                const unsigned short* __restrict__ W,
                const float* __restrict__ bias,
                const int* __restrict__ tgt,
                float* __restrict__ m_part,
                float* __restrict__ s_part,
                float* __restrict__ tlogit) {
  extern __shared__ unsigned short smem[];
  unsigned short* AsB = smem;             // [2][2][256*32] = 32768 shorts (64KB)
  unsigned short* BsB = smem + 32768;     // 64KB
  float* red_m = (float*)(smem + 65536);  // [4][256] (4KB)
  float* red_s = red_m + 1024;            // [4][256] (4KB)

  const int tid = threadIdx.x;
  const int lane = tid & 63;
  const int wid = tid >> 6;        // 0..7
  const int waveM = wid >> 2;      // 0..1 (128 rows each)
  const int waveN = wid & 3;       // 0..3 (64 cols each)
  const int q = lane >> 4;         // 0..3
  const int c = lane & 15;

  // XCD-aware bijective swizzle: 2000 blocks, 2000 % 8 == 0, chunk = 250.
  // bm fastest within a chunk -> 16 same-bn blocks (sharing the 1MB W-tile)
  // land on the same XCD's L2.
  const int swz = (blockIdx.x & 7) * (MBLK * NBLK / 8) + (blockIdx.x >> 3);
  const int bm = swz & (MBLK - 1);
  const int bn = swz >> 4;  // /MBLK

  // ---- staging source addresses (pre-swizzled global -> linear LDS dest) ----
  const int srow = tid >> 2;                          // 0..127 (2nd gld adds 128)
  const int sch = (lane & 3) ^ ((lane >> 3) & 3);     // swizzled 16B chunk 0..3
  const unsigned short* gA = X + (size_t)(bm * BM + srow) * K + sch * 8;
  const unsigned short* gB = W + (size_t)(bn * BN + srow) * K + sch * 8;
  unsigned short* const dA0 = AsB + wid * 512;        // wave-uniform dest base
  unsigned short* const dB0 = BsB + wid * 512;

  auto stA = [&](int b, int h, int t) {
    const unsigned short* s = gA + t * BK + h * 32;
    unsigned short* d = dA0 + (b * 2 + h) * 8192;
    gld16(s, d);                                  // rows 0..127 of the half
    gld16(s + (size_t)128 * K, d + 4096);         // rows 128..255
  };
  auto stB = [&](int b, int h, int t) {
    const unsigned short* s = gB + t * BK + h * 32;
    unsigned short* d = dB0 + (b * 2 + h) * 8192;
    gld16(s, d);
    gld16(s + (size_t)128 * K, d + 4096);
  };

  // ---- fragment read offsets (shorts, within one [256][32] K-half) ----
  const int chrd = (q ^ ((c >> 1) & 3)) * 8;  // swizzled chunk read offset
  int offA[8], offB[4];
#pragma unroll
  for (int mf = 0; mf < 8; ++mf) offA[mf] = (waveM * 128 + mf * 16 + c) * 32 + chrd;
#pragma unroll
  for (int nf = 0; nf < 4; ++nf) offB[nf] = (waveN * 64 + nf * 16 + c) * 32 + chrd;

  f32x4 acc[8][4];
#pragma unroll
  for (int i = 0; i < 8; ++i)
#pragma unroll
    for (int j = 0; j < 4; ++j) acc[i][j] = (f32x4){0.f, 0.f, 0.f, 0.f};
  bf16x8 bfrag[4];

  // ---- prologue: tile0 complete + tile1 k-half0 (12 loads).
  // vmcnt(8) forces the first 4 (buf0-h0, read at p1); the rest are forced by
  // the even-phase vmcnt(8) chain: p2 forces buf0-h1 (read p3), p4 forces
  // buf1-h0 (read p5), p6 forces p1,p2's loads (read p7). ----
  stA(0, 0, 0); stB(0, 0, 0);
  stA(0, 1, 0); stB(0, 1, 0);
  stA(1, 0, 1); stB(1, 0, 1);
  asm volatile("s_waitcnt vmcnt(8)" ::: "memory");
  barrier_f();

  for (int i = 0; i < KTILES / 2 - 1; ++i) {
    const int t0 = 2 * i;
    phase<0, 0, 0, -1>(AsB, BsB, offA, offB, bfrag, acc, [&] { stA(1, 1, t0 + 1); });
    phase<0, 0, 1,  8>(AsB, BsB, offA, offB, bfrag, acc, [&] { stB(1, 1, t0 + 1); });
    phase<0, 1, 0, -1>(AsB, BsB, offA, offB, bfrag, acc, [&] { stA(0, 0, t0 + 2); });
    phase<0, 1, 1,  8>(AsB, BsB, offA, offB, bfrag, acc, [&] { stB(0, 0, t0 + 2); });
    phase<1, 0, 0, -1>(AsB, BsB, offA, offB, bfrag, acc, [&] { stA(0, 1, t0 + 2); });
    phase<1, 0, 1,  8>(AsB, BsB, offA, offB, bfrag, acc, [&] { stB(0, 1, t0 + 2); });
    phase<1, 1, 0, -1>(AsB, BsB, offA, offB, bfrag, acc, [&] { stA(1, 0, t0 + 3); });
    phase<1, 1, 1,  8>(AsB, BsB, offA, offB, bfrag, acc, [&] { stB(1, 0, t0 + 3); });
  }
  {  // tail: tiles 30,31 -- only tile31's k-half1 still needs staging.
    // Waits: p2 vmcnt(8) (forces prev-p5,p6 for p3); p4 vmcnt(4) (outstanding
    // = prev-p7,p8,p1,p2; forces prev-p7,p8 for p5); p6 vmcnt(0) (forces
    // p1,p2 for p7). Once per block.
    auto nop = [&] {};
    phase<0, 0, 0, -1>(AsB, BsB, offA, offB, bfrag, acc, [&] { stA(1, 1, KTILES - 1); });
    phase<0, 0, 1,  8>(AsB, BsB, offA, offB, bfrag, acc, [&] { stB(1, 1, KTILES - 1); });
    phase<0, 1, 0, -1>(AsB, BsB, offA, offB, bfrag, acc, nop);
    phase<0, 1, 1,  4>(AsB, BsB, offA, offB, bfrag, acc, nop);
    phase<1, 0, 0, -1>(AsB, BsB, offA, offB, bfrag, acc, nop);
    phase<1, 0, 1,  0>(AsB, BsB, offA, offB, bfrag, acc, nop);
    phase<1, 1, 0, -1>(AsB, BsB, offA, offB, bfrag, acc, nop);
    phase<1, 1, 1, -1>(AsB, BsB, offA, offB, bfrag, acc, nop);
  }

  // ---- epilogue: per-row (max, sumexp) over this block's 256 columns ----
  // C/D layout (verified): col = lane&15, row = (lane>>4)*4 + reg.
  const int colBase = bn * BN + waveN * 64;
  float bvals[4];
#pragma unroll
  for (int nf = 0; nf < 4; ++nf) bvals[nf] = bias[colBase + nf * 16 + c];

#pragma unroll
  for (int mf = 0; mf < 8; ++mf) {
    const int rowBase = bm * BM + waveM * 128 + mf * 16 + q * 4;
#pragma unroll
    for (int reg = 0; reg < 4; ++reg) {
      const int grow = rowBase + reg;
      const int t = tgt[grow];
      float v[4];
      float mloc = -3.4e38f;
#pragma unroll
      for (int nf = 0; nf < 4; ++nf) {
        v[nf] = acc[mf][nf][reg] + bvals[nf];
        mloc = fmaxf(mloc, v[nf]);
        if (colBase + nf * 16 + c == t) tlogit[grow] = v[nf];  // one lane/grid
      }
#pragma unroll
      for (int off = 1; off < 16; off <<= 1) mloc = fmaxf(mloc, __shfl_xor(mloc, off));
      float sloc = 0.f;
#pragma unroll
      for (int nf = 0; nf < 4; ++nf) sloc += __expf(v[nf] - mloc);
#pragma unroll
      for (int off = 1; off < 16; off <<= 1) sloc += __shfl_xor(sloc, off);
      if (c == 0) {
        const int lrow = waveM * 128 + mf * 16 + q * 4 + reg;
        red_m[waveN * 256 + lrow] = mloc;
        red_s[waveN * 256 + lrow] = sloc;
      }
    }
  }
  __syncthreads();
  if (tid < 256) {
    const float m0 = red_m[tid],       m1 = red_m[256 + tid];
    const float m2 = red_m[512 + tid], m3 = red_m[768 + tid];
    const float mx = fmaxf(fmaxf(m0, m1), fmaxf(m2, m3));
    const float ss = red_s[tid] * __expf(m0 - mx) + red_s[256 + tid] * __expf(m1 - mx) +
                     red_s[512 + tid] * __expf(m2 - mx) + red_s[768 + tid] * __expf(m3 - mx);
    const int grow = bm * BM + tid;
    m_part[(size_t)grow * NBLK + bn] = mx;
    s_part[(size_t)grow * NBLK + bn] = ss;
  }
}

// ---------------- combine per-row partials -> per-token logp ----------------
__global__ __launch_bounds__(256)
void combine_rows(const float* __restrict__ m_part, const float* __restrict__ s_part,
                  const float* __restrict__ tlogit, const int* __restrict__ tgt,
                  float* __restrict__ logp) {
  const int row = blockIdx.x * 4 + (threadIdx.x >> 6);
  const int lane = threadIdx.x & 63;
  const float* mrow = m_part + (size_t)row * NBLK;
  const float* srow = s_part + (size_t)row * NBLK;
  const bool v1 = (lane + 64) < NBLK;  // NBLK = 125
  const float m0 = mrow[lane];
  const float s0 = srow[lane];
  const float m1 = v1 ? mrow[lane + 64] : -3.4e38f;
  const float s1 = v1 ? srow[lane + 64] : 0.f;
  float mx = fmaxf(m0, m1);
#pragma unroll
  for (int off = 32; off >= 1; off >>= 1) mx = fmaxf(mx, __shfl_xor(mx, off));
  float s = s0 * __expf(m0 - mx) + s1 * __expf(m1 - mx);
#pragma unroll
  for (int off = 32; off >= 1; off >>= 1) s += __shfl_xor(s, off);
  if (lane == 0) {
    const int t = tgt[row];
    logp[row] = (t == IGNORE) ? 0.f : (tlogit[row] - mx - logf(s));
  }
}

// ---------------- per-sequence average + SimPO loss ----------------
__global__ void finalize(const float* __restrict__ logp, const int* __restrict__ tgt,
                         float* __restrict__ out) {
  __shared__ float avg[8];
  const int w = threadIdx.x >> 6;  // 8 waves, one per sequence
  const int lane = threadIdx.x & 63;
  float s = 0.f, cnt = 0.f;
  for (int i = lane; i < Tt; i += 64) {
    const int idx = w * Tt + i;
    s += logp[idx];
    cnt += (tgt[idx] != IGNORE) ? 1.f : 0.f;
  }
#pragma unroll
  for (int off = 32; off >= 1; off >>= 1) {
    s += __shfl_xor(s, off);
    cnt += __shfl_xor(cnt, off);
  }
  if (lane == 0) avg[w] = s / fmaxf(cnt, 1.f);
  __syncthreads();
  if (threadIdx.x == 0) {
    float loss = 0.f;
#pragma unroll
    for (int p = 0; p < 4; ++p) {
      const float d = 0.1f * (avg[p] - avg[p + 4]) - 0.5f;
      const float nl = (d > 0.f) ? log1pf(expf(-d)) : (-d + log1pf(expf(d)));
      loss += nl;
    }
    out[0] = loss * 0.25f;  // / n_pairs
  }
}

extern "C" void kernel_launch(void* const* d_in, const int* in_sizes, int n_in,
                              void* d_out, int out_size, void* d_ws, size_t ws_size,
                              hipStream_t stream) {
  const float* Wf   = (const float*)d_in[0];  // lin_weight (V,H)
  const float* Xf   = (const float*)d_in[1];  // _input (B,T,H)
  const int*   tgt  = (const int*)d_in[2];    // target (B,T)
  const float* bias = (const float*)d_in[3];  // bias (V,)
  float* out = (float*)d_out;

  char* ws = (char*)d_ws;
  size_t off = 0;
  auto alloc = [&](size_t bytes) {
    void* p = ws + off;
    off += (bytes + 255) & ~(size_t)255;
    return p;
  };
  unsigned short* Xbf = (unsigned short*)alloc((size_t)M * K * 2);
  unsigned short* Wbf = (unsigned short*)alloc((size_t)N * K * 2);
  float* m_part = (float*)alloc((size_t)M * NBLK * 4);
  float* s_part = (float*)alloc((size_t)M * NBLK * 4);
  float* tlog   = (float*)alloc((size_t)M * 4);
  float* logp   = (float*)alloc((size_t)M * 4);

  cast_fused<<<4096, 256, 0, stream>>>(Xf, Xbf, Wf, Wbf);

  constexpr size_t SMEM = 2u * 2u * 256u * 32u * 2u * 2u  // A + B (128 KB)
                        + 2u * 4u * 256u * 4u;            // red_m + red_s (8 KB)
  gemm_stats<<<dim3(MBLK * NBLK), dim3(512), SMEM, stream>>>(
      Xbf, Wbf, bias, tgt, m_part, s_part, tlog);

  combine_rows<<<M / 4, 256, 0, stream>>>(m_part, s_part, tlog, tgt, logp);
  finalize<<<1, 512, 0, stream>>>(logp, tgt, out);
}

// Round 7
// 896.298 us; speedup vs baseline: 1.0240x; 1.0240x over previous
//
#include <hip/hip_runtime.h>
#include <stdint.h>
#include <math.h>

// Problem constants
constexpr int Bb = 8, Tt = 512, Hh = 2048, Vv = 32000;
constexpr int M = Bb * Tt;     // 4096 tokens
constexpr int K = Hh;          // 2048
constexpr int N = Vv;          // 32000 vocab
constexpr int BM = 256, BN = 256, BK = 64;
constexpr int MBLK = M / BM;   // 16
constexpr int NBLK = N / BN;   // 125 column blocks
constexpr int KTILES = K / BK; // 32 (even)
constexpr int IGNORE = -100;

typedef __attribute__((ext_vector_type(8))) short bf16x8;
typedef __attribute__((ext_vector_type(4))) float f32x4;
typedef __attribute__((ext_vector_type(4))) unsigned short u16x4;

__device__ inline void gld16(const void* g, void* l) {
  __builtin_amdgcn_global_load_lds(
      (const __attribute__((address_space(1))) uint32_t*)g,
      (__attribute__((address_space(3))) uint32_t*)l, 16, 0, 0);
}

__device__ __forceinline__ void barrier_f() {
  asm volatile("" ::: "memory");
  __builtin_amdgcn_s_barrier();
  asm volatile("" ::: "memory");
}

// inline-asm ds_read_b128: compiler can't see the load -> emits no auto
// lgkmcnt; ordering is OUR counted lgkmcnt + sched_barrier(0) (rule: hipcc
// hoists register-only MFMA past asm waitcnt without it).
template <int IMM>
__device__ __forceinline__ bf16x8 ds128(uint32_t a) {
  bf16x8 r;
  asm volatile("ds_read_b128 %0, %1 offset:%2" : "=v"(r) : "v"(a), "n"(IMM));
  return r;
}
template <int NW>
__device__ __forceinline__ void wait_lgkm() {
  if constexpr (NW == 0) asm volatile("s_waitcnt lgkmcnt(0)" ::: "memory");
  else if constexpr (NW == 4) asm volatile("s_waitcnt lgkmcnt(4)" ::: "memory");
  else asm volatile("s_waitcnt lgkmcnt(8)" ::: "memory");
  __builtin_amdgcn_sched_barrier(0);
}

__device__ inline unsigned short f2bf(float f) {
  union { float f; unsigned u; } x; x.f = f;
  unsigned r = x.u + 0x7fffu + ((x.u >> 16) & 1u);  // RNE
  return (unsigned short)(r >> 16);
}

// ---------------- fused fp32 -> bf16 cast for X and W (one launch) ----------
constexpr int NX4 = M * K / 4;
constexpr int NW4 = N * K / 4;
__global__ __launch_bounds__(256)
void cast_fused(const float* __restrict__ Xf, unsigned short* __restrict__ Xb,
                const float* __restrict__ Wf, unsigned short* __restrict__ Wb) {
  int64_t i = (int64_t)blockIdx.x * blockDim.x + threadIdx.x;
  const int64_t stride = (int64_t)gridDim.x * blockDim.x;
  for (; i < (int64_t)NX4 + NW4; i += stride) {
    const f32x4* s4;
    u16x4* d4;
    int64_t j;
    if (i < NX4) { s4 = (const f32x4*)Xf; d4 = (u16x4*)Xb; j = i; }
    else         { s4 = (const f32x4*)Wf; d4 = (u16x4*)Wb; j = i - NX4; }
    f32x4 v = __builtin_nontemporal_load(&s4[j]);
    u16x4 o;
    o[0] = f2bf(v[0]); o[1] = f2bf(v[1]); o[2] = f2bf(v[2]); o[3] = f2bf(v[3]);
    d4[j] = o;
  }
}

// ---------------- 256x256 8-phase GEMM, cross-phase ds_read pipelining -------
//
// R7 change: fragment ds_reads are issued ONE PHASE EARLY (after the phase's
// first barrier), via inline-asm ds_read_b128 + counted lgkmcnt, so the LDS
// pipe (~512 cyc/phase) runs underneath the MFMA pipe (~621 cyc/phase)
// instead of serializing with it (R1-R6 measured phase ~1277 cyc = sum of
// pipes; MfmaUtil stuck at 44%).
//
// Schedule per phase: {stage 1 K-half; [vmcnt(8) even phases]; barrier;
// issue NEXT phase's frag reads (4 if next is MH1, 8 if next is MH0);
// s_waitcnt lgkmcnt(n_issued)  -> forces THIS phase's frags (in-order DS);
// sched_barrier(0); setprio(1); 16 MFMA; setprio(0); barrier}.
//
// Safety (verified per-region): vmcnt(8)@even + that phase's barrier makes
// staged data visible to ALL waves >=1 phase before its (early) read; WAR on
// LDS regions holds because a reader's lgkm retires before the barrier that
// precedes the overwriting stage. Register plan: af_lo[4], af_hi[4] single
// (write-issue precedes next consume in program order), bfrag[2][4] ping-pong
// by K-subtile parity (overwritten in its consumption phase).
// Regions [buf*2+half] live at LDS bytes reg*16384 (A) / 65536+reg*16384 (B);
// region selected by the ds_read offset: immediate.

template <int PAR, int MH, int CUR, int NXT, int VM, int LGK, bool LAST, class STG>
__device__ __forceinline__ void phase(const uint32_t* aA, const uint32_t* aB,
                                      bf16x8 (&af_lo)[4], bf16x8 (&af_hi)[4],
                                      bf16x8 (&bfr)[2][4], f32x4 (&acc)[8][4],
                                      STG&& stg) {
  stg();
  if constexpr (VM == 8) asm volatile("s_waitcnt vmcnt(8)" ::: "memory");
  if constexpr (VM == 4) asm volatile("s_waitcnt vmcnt(4)" ::: "memory");
  if constexpr (VM == 0) asm volatile("s_waitcnt vmcnt(0)" ::: "memory");
  barrier_f();
  if constexpr (!LAST) {
    if constexpr (MH == 0) {  // next phase = MH1 of SAME subtile: af_hi
#pragma unroll
      for (int i = 0; i < 4; ++i) af_hi[i] = ds128<CUR * 16384>(aA[4 + i]);
    } else {  // next phase = MH0 of NEXT subtile: bfrag[!PAR] + af_lo
#pragma unroll
      for (int i = 0; i < 4; ++i) bfr[PAR ^ 1][i] = ds128<NXT * 16384>(aB[i]);
#pragma unroll
      for (int i = 0; i < 4; ++i) af_lo[i] = ds128<NXT * 16384>(aA[i]);
    }
  }
  wait_lgkm<LGK>();
  __builtin_amdgcn_s_setprio(1);
#pragma unroll
  for (int mi = 0; mi < 4; ++mi)
#pragma unroll
    for (int nf = 0; nf < 4; ++nf)
      acc[MH * 4 + mi][nf] = __builtin_amdgcn_mfma_f32_16x16x32_bf16(
          (MH == 0 ? af_lo : af_hi)[mi], bfr[PAR][nf], acc[MH * 4 + mi][nf],
          0, 0, 0);
  __builtin_amdgcn_s_setprio(0);
  barrier_f();
}

__global__ __launch_bounds__(512, 2)
void gemm_stats(const unsigned short* __restrict__ X,
                const unsigned short* __restrict__ W,
                const float* __restrict__ bias,
                const int* __restrict__ tgt,
                float* __restrict__ m_part,
                float* __restrict__ s_part,
                float* __restrict__ tlogit) {
  extern __shared__ unsigned short smem[];
  unsigned short* AsB = smem;             // [2][2][256*32] shorts (64KB)
  unsigned short* BsB = smem + 32768;     // 64KB at byte 65536
  float* red_m = (float*)(smem + 65536);  // [4][256] (4KB)
  float* red_s = red_m + 1024;            // [4][256] (4KB)

  const int tid = threadIdx.x;
  const int lane = tid & 63;
  const int wid = tid >> 6;
  const int waveM = wid >> 2;
  const int waveN = wid & 3;
  const int q = lane >> 4;
  const int c = lane & 15;

  const int swz = (blockIdx.x & 7) * (MBLK * NBLK / 8) + (blockIdx.x >> 3);
  const int bm = swz & (MBLK - 1);
  const int bn = swz >> 4;

  const int srow = tid >> 2;
  const int sch = (lane & 3) ^ ((lane >> 3) & 3);
  const unsigned short* gA = X + (size_t)(bm * BM + srow) * K + sch * 8;
  const unsigned short* gB = W + (size_t)(bn * BN + srow) * K + sch * 8;
  unsigned short* const dA0 = AsB + wid * 512;
  unsigned short* const dB0 = BsB + wid * 512;

  auto stA = [&](int b, int h, int t) {
    const unsigned short* s = gA + t * BK + h * 32;
    unsigned short* d = dA0 + (b * 2 + h) * 8192;
    gld16(s, d);
    gld16(s + (size_t)128 * K, d + 4096);
  };
  auto stB = [&](int b, int h, int t) {
    const unsigned short* s = gB + t * BK + h * 32;
    unsigned short* d = dB0 + (b * 2 + h) * 8192;
    gld16(s, d);
    gld16(s + (size_t)128 * K, d + 4096);
  };

  // ---- fragment byte addresses within region 0 (region via offset: imm) ----
  const uint32_t lds0 = __builtin_amdgcn_groupstaticsize();  // dynamic LDS base
  const int chrd = (q ^ ((c >> 1) & 3)) * 8;
  uint32_t aA[8], aB[4];
#pragma unroll
  for (int mf = 0; mf < 8; ++mf)
    aA[mf] = lds0 + 2u * ((waveM * 128 + mf * 16 + c) * 32 + chrd);
#pragma unroll
  for (int nf = 0; nf < 4; ++nf)
    aB[nf] = lds0 + 65536u + 2u * ((waveN * 64 + nf * 16 + c) * 32 + chrd);

  f32x4 acc[8][4];
#pragma unroll
  for (int i = 0; i < 8; ++i)
#pragma unroll
    for (int j = 0; j < 4; ++j) acc[i][j] = (f32x4){0.f, 0.f, 0.f, 0.f};
  bf16x8 af_lo[4], af_hi[4], bfr[2][4];

  // ---- prologue: tile0 (regions 0,1) + tile1 k-half0 (region 2), 12 loads.
  // vmcnt(8) forces region0; regions 1,2,3 forced by the even-phase vmcnt(8)
  // chain one barrier before their early reads (verified per-region). ----
  stA(0, 0, 0); stB(0, 0, 0);
  stA(0, 1, 0); stB(0, 1, 0);
  stA(1, 0, 1); stB(1, 0, 1);
  asm volatile("s_waitcnt vmcnt(8)" ::: "memory");
  barrier_f();
  // subtile-0 fragment reads (forced complete by p1's lgkmcnt(4))
#pragma unroll
  for (int i = 0; i < 4; ++i) bfr[0][i] = ds128<0>(aB[i]);
#pragma unroll
  for (int i = 0; i < 4; ++i) af_lo[i] = ds128<0>(aA[i]);

  for (int i = 0; i < KTILES / 2 - 1; ++i) {
    const int t0 = 2 * i;
    phase<0, 0, 0, 0, -1, 4, false>(aA, aB, af_lo, af_hi, bfr, acc, [&] { stA(1, 1, t0 + 1); });
    phase<0, 1, 0, 1,  8, 8, false>(aA, aB, af_lo, af_hi, bfr, acc, [&] { stB(1, 1, t0 + 1); });
    phase<1, 0, 1, 1, -1, 4, false>(aA, aB, af_lo, af_hi, bfr, acc, [&] { stA(0, 0, t0 + 2); });
    phase<1, 1, 1, 2,  8, 8, false>(aA, aB, af_lo, af_hi, bfr, acc, [&] { stB(0, 0, t0 + 2); });
    phase<0, 0, 2, 2, -1, 4, false>(aA, aB, af_lo, af_hi, bfr, acc, [&] { stA(0, 1, t0 + 2); });
    phase<0, 1, 2, 3,  8, 8, false>(aA, aB, af_lo, af_hi, bfr, acc, [&] { stB(0, 1, t0 + 2); });
    phase<1, 0, 3, 3, -1, 4, false>(aA, aB, af_lo, af_hi, bfr, acc, [&] { stA(1, 0, t0 + 3); });
    phase<1, 1, 3, 0,  8, 8, false>(aA, aB, af_lo, af_hi, bfr, acc, [&] { stB(1, 0, t0 + 3); });
  }
  {  // tail: tiles 30,31. vmcnt: p2=8 (forces prev p5,p6), p4=4 (prev p7,p8),
     // p6=0 (tail p1,p2). Last phase: no early read, lgkmcnt(0).
    auto nop = [&] {};
    phase<0, 0, 0, 0, -1, 4, false>(aA, aB, af_lo, af_hi, bfr, acc, [&] { stA(1, 1, KTILES - 1); });
    phase<0, 1, 0, 1,  8, 8, false>(aA, aB, af_lo, af_hi, bfr, acc, [&] { stB(1, 1, KTILES - 1); });
    phase<1, 0, 1, 1, -1, 4, false>(aA, aB, af_lo, af_hi, bfr, acc, nop);
    phase<1, 1, 1, 2,  4, 8, false>(aA, aB, af_lo, af_hi, bfr, acc, nop);
    phase<0, 0, 2, 2, -1, 4, false>(aA, aB, af_lo, af_hi, bfr, acc, nop);
    phase<0, 1, 2, 3,  0, 8, false>(aA, aB, af_lo, af_hi, bfr, acc, nop);
    phase<1, 0, 3, 3, -1, 4, false>(aA, aB, af_lo, af_hi, bfr, acc, nop);
    phase<1, 1, 3, 0, -1, 0, true >(aA, aB, af_lo, af_hi, bfr, acc, nop);
  }

  // ---- epilogue: per-row (max, sumexp) over this block's 256 columns ----
  const int colBase = bn * BN + waveN * 64;
  float bvals[4];
#pragma unroll
  for (int nf = 0; nf < 4; ++nf) bvals[nf] = bias[colBase + nf * 16 + c];

#pragma unroll
  for (int mf = 0; mf < 8; ++mf) {
    const int rowBase = bm * BM + waveM * 128 + mf * 16 + q * 4;
#pragma unroll
    for (int reg = 0; reg < 4; ++reg) {
      const int grow = rowBase + reg;
      const int t = tgt[grow];
      float v[4];
      float mloc = -3.4e38f;
#pragma unroll
      for (int nf = 0; nf < 4; ++nf) {
        v[nf] = acc[mf][nf][reg] + bvals[nf];
        mloc = fmaxf(mloc, v[nf]);
        if (colBase + nf * 16 + c == t) tlogit[grow] = v[nf];
      }
#pragma unroll
      for (int off = 1; off < 16; off <<= 1) mloc = fmaxf(mloc, __shfl_xor(mloc, off));
      float sloc = 0.f;
#pragma unroll
      for (int nf = 0; nf < 4; ++nf) sloc += __expf(v[nf] - mloc);
#pragma unroll
      for (int off = 1; off < 16; off <<= 1) sloc += __shfl_xor(sloc, off);
      if (c == 0) {
        const int lrow = waveM * 128 + mf * 16 + q * 4 + reg;
        red_m[waveN * 256 + lrow] = mloc;
        red_s[waveN * 256 + lrow] = sloc;
      }
    }
  }
  __syncthreads();
  if (tid < 256) {
    const float m0 = red_m[tid],       m1 = red_m[256 + tid];
    const float m2 = red_m[512 + tid], m3 = red_m[768 + tid];
    const float mx = fmaxf(fmaxf(m0, m1), fmaxf(m2, m3));
    const float ss = red_s[tid] * __expf(m0 - mx) + red_s[256 + tid] * __expf(m1 - mx) +
                     red_s[512 + tid] * __expf(m2 - mx) + red_s[768 + tid] * __expf(m3 - mx);
    const int grow = bm * BM + tid;
    m_part[(size_t)grow * NBLK + bn] = mx;
    s_part[(size_t)grow * NBLK + bn] = ss;
  }
}

// ---------------- combine per-row partials -> per-token logp ----------------
__global__ __launch_bounds__(256)
void combine_rows(const float* __restrict__ m_part, const float* __restrict__ s_part,
                  const float* __restrict__ tlogit, const int* __restrict__ tgt,
                  float* __restrict__ logp) {
  const int row = blockIdx.x * 4 + (threadIdx.x >> 6);
  const int lane = threadIdx.x & 63;
  const float* mrow = m_part + (size_t)row * NBLK;
  const float* srow = s_part + (size_t)row * NBLK;
  const bool v1 = (lane + 64) < NBLK;  // NBLK = 125
  const float m0 = mrow[lane];
  const float s0 = srow[lane];
  const float m1 = v1 ? mrow[lane + 64] : -3.4e38f;
  const float s1 = v1 ? srow[lane + 64] : 0.f;
  float mx = fmaxf(m0, m1);
#pragma unroll
  for (int off = 32; off >= 1; off >>= 1) mx = fmaxf(mx, __shfl_xor(mx, off));
  float s = s0 * __expf(m0 - mx) + s1 * __expf(m1 - mx);
#pragma unroll
  for (int off = 32; off >= 1; off >>= 1) s += __shfl_xor(s, off);
  if (lane == 0) {
    const int t = tgt[row];
    logp[row] = (t == IGNORE) ? 0.f : (tlogit[row] - mx - logf(s));
  }
}

// ---------------- per-sequence average + SimPO loss ----------------
__global__ void finalize(const float* __restrict__ logp, const int* __restrict__ tgt,
                         float* __restrict__ out) {
  __shared__ float avg[8];
  const int w = threadIdx.x >> 6;
  const int lane = threadIdx.x & 63;
  float s = 0.f, cnt = 0.f;
  for (int i = lane; i < Tt; i += 64) {
    const int idx = w * Tt + i;
    s += logp[idx];
    cnt += (tgt[idx] != IGNORE) ? 1.f : 0.f;
  }
#pragma unroll
  for (int off = 32; off >= 1; off >>= 1) {
    s += __shfl_xor(s, off);
    cnt += __shfl_xor(cnt, off);
  }
  if (lane == 0) avg[w] = s / fmaxf(cnt, 1.f);
  __syncthreads();
  if (threadIdx.x == 0) {
    float loss = 0.f;
#pragma unroll
    for (int p = 0; p < 4; ++p) {
      const float d = 0.1f * (avg[p] - avg[p + 4]) - 0.5f;
      const float nl = (d > 0.f) ? log1pf(expf(-d)) : (-d + log1pf(expf(d)));
      loss += nl;
    }
    out[0] = loss * 0.25f;
  }
}

extern "C" void kernel_launch(void* const* d_in, const int* in_sizes, int n_in,
                              void* d_out, int out_size, void* d_ws, size_t ws_size,
                              hipStream_t stream) {
  const float* Wf   = (const float*)d_in[0];
  const float* Xf   = (const float*)d_in[1];
  const int*   tgt  = (const int*)d_in[2];
  const float* bias = (const float*)d_in[3];
  float* out = (float*)d_out;

  char* ws = (char*)d_ws;
  size_t off = 0;
  auto alloc = [&](size_t bytes) {
    void* p = ws + off;
    off += (bytes + 255) & ~(size_t)255;
    return p;
  };
  unsigned short* Xbf = (unsigned short*)alloc((size_t)M * K * 2);
  unsigned short* Wbf = (unsigned short*)alloc((size_t)N * K * 2);
  float* m_part = (float*)alloc((size_t)M * NBLK * 4);
  float* s_part = (float*)alloc((size_t)M * NBLK * 4);
  float* tlog   = (float*)alloc((size_t)M * 4);
  float* logp   = (float*)alloc((size_t)M * 4);

  cast_fused<<<4096, 256, 0, stream>>>(Xf, Xbf, Wf, Wbf);

  constexpr size_t SMEM = 2u * 2u * 256u * 32u * 2u * 2u  // A + B (128 KB)
                        + 2u * 4u * 256u * 4u;            // red_m + red_s (8 KB)
  gemm_stats<<<dim3(MBLK * NBLK), dim3(512), SMEM, stream>>>(
      Xbf, Wbf, bias, tgt, m_part, s_part, tlog);

  combine_rows<<<M / 4, 256, 0, stream>>>(m_part, s_part, tlog, tgt, logp);
  finalize<<<1, 512, 0, stream>>>(logp, tgt, out);
}